// Round 12
// baseline (146.986 us; speedup 1.0000x reference)
//
#include <hip/hip_runtime.h>

#define NG 48
#define NT 6                    // 4 A tiles per axis (8 cells)
#define NTILES (NT * NT * NT)   // 216
#define CHUNK 512               // atoms per bin block
#define NCHUNK 32               // 16384 / 512
#define SUBCAP 96               // per-(tile,chunk) sub-list capacity; lambda~32
// ws layout:
//   [0,      82944)  int cntc[3*216][NCHUNK]
//   [131072, +4.0M)  u16 lists[3*216][NCHUNK][SUBCAP]
#define LISTS_OFF 131072

__device__ __forceinline__ float type_r(int type) {
    return (type == 0) ? 1.7f : ((type == 1) ? 1.55f : 1.52f);
}

// Phase 1: one block per (512-atom chunk, type). LDS histogram assigns each
// (atom, tile) insertion a slot in the chunk-PRIVATE sub-list -> plain global
// stores only (no global atomics, no pre-zeroed counters, no memset dispatch).
// Each block also plain-stores its 216 per-tile counts.
__global__ __launch_bounds__(512) void bin_kernel(
    const float* __restrict__ vC, const float* __restrict__ vN,
    const float* __restrict__ vO, int* __restrict__ cntc,
    unsigned short* __restrict__ lists, int natoms)
{
    const int type  = blockIdx.y;
    const int chunk = blockIdx.x;
    const float r = type_r(type);
    const float b = 1.5f * r + 1e-3f;
    const float* __restrict__ vecs = (type == 0) ? vC : ((type == 1) ? vN : vO);
    const int tid  = threadIdx.x;
    const int atom = chunk * CHUNK + tid;

    __shared__ int lfill[NTILES];
    if (tid < NTILES) lfill[tid] = 0;
    __syncthreads();

    int x0 = 1, x1 = 0, y0 = 1, y1 = 0, z0 = 1, z1 = 0;
    if (atom < natoms) {
        const float vx = vecs[3 * atom + 0] + 23.5f;  // vec = raw + 24 - 0.5
        const float vy = vecs[3 * atom + 1] + 23.5f;
        const float vz = vecs[3 * atom + 2] + 23.5f;
        // tile t intersects the 1.5r halo iff 4t > v - b - 3.5 and 4t < v + b
        x0 = max(0,      (int)floorf((vx - 3.5f - b) * 0.25f) + 1);
        x1 = min(NT - 1, (int)ceilf ((vx + b)        * 0.25f) - 1);
        y0 = max(0,      (int)floorf((vy - 3.5f - b) * 0.25f) + 1);
        y1 = min(NT - 1, (int)ceilf ((vy + b)        * 0.25f) - 1);
        z0 = max(0,      (int)floorf((vz - 3.5f - b) * 0.25f) + 1);
        z1 = min(NT - 1, (int)ceilf ((vz + b)        * 0.25f) - 1);
    }
    const bool has = (x0 <= x1) & (y0 <= y1) & (z0 <= z1);

    if (has)
        for (int tx = x0; tx <= x1; ++tx)
            for (int ty = y0; ty <= y1; ++ty)
                for (int tz = z0; tz <= z1; ++tz) {
                    const int tl = (tx * NT + ty) * NT + tz;
                    const int p  = atomicAdd(&lfill[tl], 1);   // LDS only
                    if (p < SUBCAP)
                        lists[((size_t)(type * NTILES + tl) * NCHUNK + chunk)
                              * SUBCAP + p] = (unsigned short)atom;
                }
    __syncthreads();

    if (tid < NTILES)
        cntc[(type * NTILES + tid) * NCHUNK + chunk] = min(lfill[tid], SUBCAP);
}

// Phase 2: one 256-thread block per (tile, type). Prefix-sum the 32 chunk
// counts in LDS; stage 256-atom batches (virtual index -> (chunk,slot) via
// 5-step LDS binary search); evaluate 2 cells/thread (R10's proven loop);
// plain-store all 512 cells (zeros for inactive tiles). No atomics/reduce.
__global__ __launch_bounds__(256) void gather_tile(
    const float* __restrict__ vC, const float* __restrict__ vN,
    const float* __restrict__ vO, const int* __restrict__ cntc,
    const unsigned short* __restrict__ lists, float* __restrict__ out)
{
    const int type = blockIdx.y;
    const int t    = blockIdx.x;
    const float r = type_r(type);
    const float* __restrict__ vecs = (type == 0) ? vC : ((type == 1) ? vN : vO);

    const int lt = type * NTILES + t;
    const int tx = t / (NT * NT);
    const int ty = (t / NT) % NT;
    const int tz = t % NT;

    const int tid = threadIdx.x;
    const int lx  = tid >> 6;          // 0..3 -> cells x and x+4
    const int ly  = (tid >> 3) & 7;
    const int lz  = tid & 7;

    const float b      = 1.5f * r;
    const float r15sq  = b * b;
    const float rr     = r * r;
    const float E2     = 7.3890562f;
    const float c2a    = 4.0f / (E2 * rr);
    const float c2b    = 12.0f / (E2 * r);
    const float c2c    = 9.0f / E2;
    const float n2orr  = -2.0f / rr;

    const float px0 = 0.5f * (float)(tx * 8 + lx);
    const float px1 = px0 + 2.0f;
    const float py  = 0.5f * (float)(ty * 8 + ly);
    const float pz  = 0.5f * (float)(tz * 8 + lz);

    __shared__ int    ps[NCHUNK + 1];
    __shared__ float4 sa[256];

    if (tid < NCHUNK) ps[tid + 1] = cntc[lt * NCHUNK + tid];
    __syncthreads();
    if (tid == 0) {
        ps[0] = 0;
        for (int c = 0; c < NCHUNK; ++c) ps[c + 1] += ps[c];  // inclusive->offsets
    }
    __syncthreads();
    const int total = ps[NCHUNK];

    float acc0 = 0.0f, acc1 = 0.0f;

    const unsigned short* __restrict__ lbase =
        lists + (size_t)lt * NCHUNK * SUBCAP;

    for (int base = 0; base < total; base += 256) {
        const int m = min(256, total - base);
        if (tid < m) {
            const int g = base + tid;
            int lo = 0, hi = NCHUNK;               // ps[lo] <= g < ps[lo+1]
            while (hi - lo > 1) {
                const int mid = (lo + hi) >> 1;
                if (ps[mid] <= g) lo = mid; else hi = mid;
            }
            const int idx = (int)lbase[(size_t)lo * SUBCAP + (g - ps[lo])];
            sa[tid] = make_float4(vecs[3 * idx + 0] + 23.5f,
                                  vecs[3 * idx + 1] + 23.5f,
                                  vecs[3 * idx + 2] + 23.5f, 0.0f);
        }
        __syncthreads();

        for (int j = 0; j < m; ++j) {
            const float4 a = sa[j];               // one b128 LDS broadcast
            const float dy  = a.y - py;
            const float dz  = a.z - pz;
            const float syz = fmaf(dy, dy, dz * dz);
            const float dx0 = a.x - px0;
            const float d2a = fmaf(dx0, dx0, syz);
            const float dx1 = a.x - px1;
            const float d2b = fmaf(dx1, dx1, syz);
            const bool h0 = d2a < r15sq;
            const bool h1 = d2b < r15sq;
            if (__ballot(h0 | h1) == 0ull) continue;   // whole-wave miss cull
            if (h0) {
                const float d = sqrtf(d2a);
                acc0 += (d < r) ? __expf(n2orr * d2a)
                                : fmaf(c2a, d2a, fmaf(-c2b, d, c2c));
            }
            if (h1) {
                const float d = sqrtf(d2b);
                acc1 += (d < r) ? __expf(n2orr * d2b)
                                : fmaf(c2a, d2b, fmaf(-c2b, d, c2c));
            }
        }
        __syncthreads();
    }

    const int X0 = tx * 8 + lx;
    const int Y  = ty * 8 + ly;
    const int Z  = tz * 8 + lz;
    float* __restrict__ o = out + (size_t)type * NG * NG * NG;
    o[((X0      * NG) + Y) * NG + Z] = acc0;
    o[(((X0 + 4) * NG) + Y) * NG + Z] = acc1;
}

extern "C" void kernel_launch(void* const* d_in, const int* in_sizes, int n_in,
                              void* d_out, int out_size, void* d_ws, size_t ws_size,
                              hipStream_t stream) {
    const float* vC = (const float*)d_in[0];
    const float* vN = (const float*)d_in[1];
    const float* vO = (const float*)d_in[2];
    float* out = (float*)d_out;

    int* cntc = (int*)d_ws;
    unsigned short* lists = (unsigned short*)((char*)d_ws + LISTS_OFF);

    const int natoms = in_sizes[0] / 3;           // 16384
    const int nchunk = (natoms + CHUNK - 1) / CHUNK;   // 32 (NCHUNK)

    dim3 bgrid(nchunk, 3, 1);
    bin_kernel<<<bgrid, CHUNK, 0, stream>>>(vC, vN, vO, cntc, lists, natoms);

    dim3 ggrid(NTILES, 3, 1);
    gather_tile<<<ggrid, 256, 0, stream>>>(vC, vN, vO, cntc, lists, out);
}

// Round 13
// 39.496 us; speedup vs baseline: 3.7215x; 3.7215x over previous
//
#include <hip/hip_runtime.h>

#define NG 48
#define NT 6                    // 4 A tiles per axis (8 cells)
#define NTILES (NT * NT * NT)   // 216
#define CHUNK 512               // atoms per bin block
#define NCHUNK 32               // 16384 / 512
#define SUBCAP 96               // per-(tile,chunk) capacity; lambda ~32, P(ovf)~e^-45
#define NSEG 8                  // gather segments = chunk groups of 4
#define CPSEG (NCHUNK / NSEG)   // 4 chunks per segment
// ws layout:
//   [0,      82944)   int cntc[3*216][NCHUNK]
//   [131072, +3.98M)  u16 lists[3*216][NCHUNK][SUBCAP]
//   [8MiB,   +10.6M)  float copies[3*216][NSEG][512]
#define LISTS_OFF  131072
#define COPIES_OFF (8u << 20)

__device__ __forceinline__ float type_r(int type) {
    return (type == 0) ? 1.7f : ((type == 1) ? 1.55f : 1.52f);
}

// Phase 1: one block per (512-atom chunk, type). LDS histogram assigns each
// (atom,tile) insertion a slot in the chunk-PRIVATE sub-list -> plain global
// stores only (no global atomics, no memset dispatch). Also stores counts.
__global__ __launch_bounds__(512) void bin_kernel(
    const float* __restrict__ vC, const float* __restrict__ vN,
    const float* __restrict__ vO, int* __restrict__ cntc,
    unsigned short* __restrict__ lists, int natoms)
{
    const int type  = blockIdx.y;
    const int chunk = blockIdx.x;
    const float r = type_r(type);
    const float b = 1.5f * r + 1e-3f;
    const float* __restrict__ vecs = (type == 0) ? vC : ((type == 1) ? vN : vO);
    const int tid  = threadIdx.x;
    const int atom = chunk * CHUNK + tid;

    __shared__ int lfill[NTILES];
    if (tid < NTILES) lfill[tid] = 0;
    __syncthreads();

    int x0 = 1, x1 = 0, y0 = 1, y1 = 0, z0 = 1, z1 = 0;
    if (atom < natoms) {
        const float vx = vecs[3 * atom + 0] + 23.5f;  // vec = raw + 24 - 0.5
        const float vy = vecs[3 * atom + 1] + 23.5f;
        const float vz = vecs[3 * atom + 2] + 23.5f;
        // tile t intersects the 1.5r halo iff 4t > v - b - 3.5 and 4t < v + b
        x0 = max(0,      (int)floorf((vx - 3.5f - b) * 0.25f) + 1);
        x1 = min(NT - 1, (int)ceilf ((vx + b)        * 0.25f) - 1);
        y0 = max(0,      (int)floorf((vy - 3.5f - b) * 0.25f) + 1);
        y1 = min(NT - 1, (int)ceilf ((vy + b)        * 0.25f) - 1);
        z0 = max(0,      (int)floorf((vz - 3.5f - b) * 0.25f) + 1);
        z1 = min(NT - 1, (int)ceilf ((vz + b)        * 0.25f) - 1);
    }
    const bool has = (x0 <= x1) & (y0 <= y1) & (z0 <= z1);

    if (has)
        for (int tx = x0; tx <= x1; ++tx)
            for (int ty = y0; ty <= y1; ++ty)
                for (int tz = z0; tz <= z1; ++tz) {
                    const int tl = (tx * NT + ty) * NT + tz;
                    const int p  = atomicAdd(&lfill[tl], 1);   // LDS only
                    if (p < SUBCAP)
                        lists[((size_t)(type * NTILES + tl) * NCHUNK + chunk)
                              * SUBCAP + p] = (unsigned short)atom;
                }
    __syncthreads();

    if (tid < NTILES)
        cntc[(type * NTILES + tid) * NCHUNK + chunk] = min(lfill[tid], SUBCAP);
}

// Phase 2: one 256-thread block per (segment, tile, type), segment-major.
// Segment s owns chunks [4s, 4s+4). Stages its atoms (prefix over 4 chunk
// counts + 2-step search), evaluates 2 cells/thread with whole-wave cull,
// stores 512 partials iff the segment is non-empty.
__global__ __launch_bounds__(256) void gather_seg(
    const float* __restrict__ vC, const float* __restrict__ vN,
    const float* __restrict__ vO, const int* __restrict__ cntc,
    const unsigned short* __restrict__ lists, float* __restrict__ copies)
{
    const int type = blockIdx.y;
    const int s = blockIdx.x / NTILES;        // segment-major spread
    const int t = blockIdx.x - s * NTILES;
    const int lt = type * NTILES + t;

    __shared__ int ps[CPSEG + 1];
    __shared__ float4 sa[256];

    const int tid = threadIdx.x;
    if (tid == 0) {
        int acc = 0;
        ps[0] = 0;
        #pragma unroll
        for (int c = 0; c < CPSEG; ++c) {
            acc += cntc[lt * NCHUNK + s * CPSEG + c];
            ps[c + 1] = acc;
        }
    }
    __syncthreads();
    const int total = ps[CPSEG];
    if (total == 0) return;                   // empty segment: no work, no store

    const float r = type_r(type);
    const float* __restrict__ vecs = (type == 0) ? vC : ((type == 1) ? vN : vO);

    const int tx = t / (NT * NT);
    const int ty = (t / NT) % NT;
    const int tz = t % NT;
    const int lx  = tid >> 6;          // 0..3 -> cells x and x+4
    const int ly  = (tid >> 3) & 7;
    const int lz  = tid & 7;

    const float b      = 1.5f * r;
    const float r15sq  = b * b;
    const float rr     = r * r;
    const float E2     = 7.3890562f;
    const float c2a    = 4.0f / (E2 * rr);
    const float c2b    = 12.0f / (E2 * r);
    const float c2c    = 9.0f / E2;
    const float n2orr  = -2.0f / rr;

    const float px0 = 0.5f * (float)(tx * 8 + lx);
    const float px1 = px0 + 2.0f;
    const float py  = 0.5f * (float)(ty * 8 + ly);
    const float pz  = 0.5f * (float)(tz * 8 + lz);

    const unsigned short* __restrict__ lbase =
        lists + ((size_t)lt * NCHUNK + s * CPSEG) * SUBCAP;

    float acc0 = 0.0f, acc1 = 0.0f;

    for (int base = 0; base < total; base += 256) {
        const int m = min(256, total - base);
        if (tid < m) {
            const int g = base + tid;
            int c = (ps[2] <= g) ? 2 : 0;               // 2-step search over 4
            c += (ps[c + 1] <= g) ? 1 : 0;
            const int idx = (int)lbase[(size_t)c * SUBCAP + (g - ps[c])];
            sa[tid] = make_float4(vecs[3 * idx + 0] + 23.5f,
                                  vecs[3 * idx + 1] + 23.5f,
                                  vecs[3 * idx + 2] + 23.5f, 0.0f);
        }
        __syncthreads();

        for (int j = 0; j < m; ++j) {
            const float4 a = sa[j];               // one b128 LDS broadcast
            const float dy  = a.y - py;
            const float dz  = a.z - pz;
            const float syz = fmaf(dy, dy, dz * dz);
            const float dx0 = a.x - px0;
            const float d2a = fmaf(dx0, dx0, syz);
            const float dx1 = a.x - px1;
            const float d2b = fmaf(dx1, dx1, syz);
            const bool h0 = d2a < r15sq;
            const bool h1 = d2b < r15sq;
            if (__ballot(h0 | h1) == 0ull) continue;   // whole-wave miss cull
            if (h0) {
                const float d = sqrtf(d2a);
                acc0 += (d < r) ? __expf(n2orr * d2a)
                                : fmaf(c2a, d2a, fmaf(-c2b, d, c2c));
            }
            if (h1) {
                const float d = sqrtf(d2b);
                acc1 += (d < r) ? __expf(n2orr * d2b)
                                : fmaf(c2a, d2b, fmaf(-c2b, d, c2c));
            }
        }
        __syncthreads();
    }

    float* __restrict__ cp = copies + ((size_t)lt * NSEG + s) * 512;
    cp[tid]       = acc0;
    cp[tid + 256] = acc1;
}

// Phase 3: one block per (tile,type). Derives per-segment activity from the
// chunk counts (same condition gather used), sums stored segments in fixed
// order, writes the tile's 512 output cells once (zeros for inactive tiles).
__global__ __launch_bounds__(256) void reduce_kernel(
    const int* __restrict__ cntc, const float* __restrict__ copies,
    float* __restrict__ out)
{
    const int type = blockIdx.y;
    const int t = blockIdx.x;
    const int lt = type * NTILES + t;
    const int tid = threadIdx.x;

    __shared__ int segact[NSEG];
    if (tid < NSEG) {
        int acc = 0;
        #pragma unroll
        for (int c = 0; c < CPSEG; ++c)
            acc += cntc[lt * NCHUNK + tid * CPSEG + c];
        segact[tid] = acc;
    }
    __syncthreads();

    const float* __restrict__ cp = copies + ((size_t)lt * NSEG) * 512;
    float o0 = 0.0f, o1 = 0.0f;
    #pragma unroll
    for (int ss = 0; ss < NSEG; ++ss) {
        if (segact[ss] > 0) {
            o0 += cp[(size_t)ss * 512 + tid];
            o1 += cp[(size_t)ss * 512 + 256 + tid];
        }
    }

    const int tx = t / (NT * NT);
    const int ty = (t / NT) % NT;
    const int tz = t % NT;
    const int lx  = tid >> 6;
    const int ly  = (tid >> 3) & 7;
    const int lz  = tid & 7;
    const int X0 = tx * 8 + lx;
    const int Y  = ty * 8 + ly;
    const int Z  = tz * 8 + lz;
    float* __restrict__ o = out + (size_t)type * NG * NG * NG;
    o[((X0      * NG) + Y) * NG + Z] = o0;
    o[(((X0 + 4) * NG) + Y) * NG + Z] = o1;
}

extern "C" void kernel_launch(void* const* d_in, const int* in_sizes, int n_in,
                              void* d_out, int out_size, void* d_ws, size_t ws_size,
                              hipStream_t stream) {
    const float* vC = (const float*)d_in[0];
    const float* vN = (const float*)d_in[1];
    const float* vO = (const float*)d_in[2];
    float* out = (float*)d_out;

    int* cntc = (int*)d_ws;
    unsigned short* lists = (unsigned short*)((char*)d_ws + LISTS_OFF);
    float* copies = (float*)((char*)d_ws + COPIES_OFF);

    const int natoms = in_sizes[0] / 3;               // 16384
    const int nchunk = (natoms + CHUNK - 1) / CHUNK;  // 32 == NCHUNK

    dim3 bgrid(nchunk, 3, 1);
    bin_kernel<<<bgrid, CHUNK, 0, stream>>>(vC, vN, vO, cntc, lists, natoms);

    dim3 ggrid(NTILES * NSEG, 3, 1);
    gather_seg<<<ggrid, 256, 0, stream>>>(vC, vN, vO, cntc, lists, copies);

    dim3 rgrid(NTILES, 3, 1);
    reduce_kernel<<<rgrid, 256, 0, stream>>>(cntc, copies, out);
}